// Round 3
// baseline (296.337 us; speedup 1.0000x reference)
//
#include <hip/hip_runtime.h>
#include <hip/hip_bf16.h>

#define DD 256
#define KC 1024
#define BM 32
#define XLD 264   // x tile row stride (bf16 elems): 528 B
#define QLD 136   // q tile row stride (bf16 elems): 272 B

typedef __attribute__((ext_vector_type(4))) float f32x4;
typedef __attribute__((ext_vector_type(8))) short bf16x8;
typedef __attribute__((ext_vector_type(4))) short s16x4;

static __device__ __forceinline__ short f2bf(float f) {
    union { float f; unsigned u; } v; v.f = f;
    unsigned u = v.u;
    unsigned r = u + 0x7fffu + ((u >> 16) & 1u);
    return (short)(r >> 16);
}

// ---------------------------------------------------------------------------
// prep: W fp32 [1024][256] -> wbf bf16 [1024][256], wtbf bf16 [256][1024],
//       wsq[k] = sum_d W[k][d]^2 / 256
// ---------------------------------------------------------------------------
__global__ void prep_kernel(const float* __restrict__ w, short* __restrict__ wbf,
                            short* __restrict__ wtbf, float* __restrict__ wsq) {
    const int cod = blockIdx.x;
    const int d   = threadIdx.x;           // 256 threads
    float v = w[cod * DD + d];
    short b = f2bf(v);
    wbf[cod * DD + d] = b;
    wtbf[d * KC + cod] = b;
    float s = v * v;
    #pragma unroll
    for (int m = 32; m >= 1; m >>= 1) s += __shfl_xor(s, m, 64);
    __shared__ float ps[4];
    const int wave = threadIdx.x >> 6, lane = threadIdx.x & 63;
    if (lane == 0) ps[wave] = s;
    __syncthreads();
    if (threadIdx.x == 0) {
        wsq[cod] = (ps[0] + ps[1] + ps[2] + ps[3]) * (1.0f / (float)DD);
    }
}

// ---------------------------------------------------------------------------
// Fused kernel: per block 32 rows, 8 waves.
// x/qdist/quant use non-temporal accesses so the streamed 400 MB does not
// evict the 1 MB codebook working set from L2 (W is re-read by every block).
// W loads are double-buffer prefetched to deepen MLP.
// ---------------------------------------------------------------------------
__global__ __launch_bounds__(512, 3) void fused_kernel(
    const float* __restrict__ x, const short* __restrict__ wbf,
    const short* __restrict__ wtbf, const float* __restrict__ wsq,
    float* __restrict__ qdist, float* __restrict__ quant) {
    __shared__ union {
        short xs[BM * XLD];        // 16,896 B  (phase 1-2)
        short qs[8][BM][QLD];      // 69,632 B  (phase 4-5)
    } u;
    __shared__ float red[8][BM];

    const int t    = threadIdx.x;
    const int wave = t >> 6;
    const int lane = t & 63;
    const int lhi  = lane >> 4, llo = lane & 15;
    const long rowbase = (long)blockIdx.x * BM;

    // ---- phase 1: stage x tile (32 x 256 fp32) -> bf16 LDS (nt loads) ----
    const f32x4* xv = (const f32x4*)(x + rowbase * DD);
    #pragma unroll
    for (int i = 0; i < 4; i++) {
        int f4 = t + i * 512;          // row = f4/64, col4 = f4%64
        f32x4 v = __builtin_nontemporal_load(xv + f4);
        int row = f4 >> 6, c4 = f4 & 63;
        s16x4 sv;
        sv[0] = f2bf(v[0]); sv[1] = f2bf(v[1]); sv[2] = f2bf(v[2]); sv[3] = f2bf(v[3]);
        *(s16x4*)(u.xs + row * XLD + c4 * 4) = sv;
    }

    // hoist wsq loads (tiny, L2)
    const int cb = wave * 128;
    float ws[8];
    #pragma unroll
    for (int ct = 0; ct < 8; ct++) ws[ct] = wsq[cb + ct * 16 + llo];

    __syncthreads();

    // ---- phase 2: cross + exp for this wave's 128 codes (prefetched) ----
    float e[8][2][4];
    float rs0[4] = {0.f, 0.f, 0.f, 0.f};
    float rs1[4] = {0.f, 0.f, 0.f, 0.f};

    const short* xr0 = u.xs + llo * XLD + lhi * 8;
    const short* xr1 = xr0 + 16 * XLD;

    bf16x8 wcur[8], wnxt[8];
    {
        const short* wrow = wbf + (size_t)(cb + llo) * DD + lhi * 8;
        #pragma unroll
        for (int kk = 0; kk < 8; kk++) wcur[kk] = *(const bf16x8*)(wrow + kk * 32);
    }

    #pragma unroll
    for (int ct = 0; ct < 8; ct++) {
        if (ct < 7) {
            const short* wrow = wbf + (size_t)(cb + (ct + 1) * 16 + llo) * DD + lhi * 8;
            #pragma unroll
            for (int kk = 0; kk < 8; kk++) wnxt[kk] = *(const bf16x8*)(wrow + kk * 32);
        }
        f32x4 acc0 = {0.f, 0.f, 0.f, 0.f};
        f32x4 acc1 = {0.f, 0.f, 0.f, 0.f};
        #pragma unroll
        for (int kk = 0; kk < 8; kk++) {
            bf16x8 a0 = *(const bf16x8*)(xr0 + kk * 32);
            bf16x8 a1 = *(const bf16x8*)(xr1 + kk * 32);
            acc0 = __builtin_amdgcn_mfma_f32_16x16x32_bf16(a0, wcur[kk], acc0, 0, 0, 0);
            acc1 = __builtin_amdgcn_mfma_f32_16x16x32_bf16(a1, wcur[kk], acc1, 0, 0, 0);
        }
        #pragma unroll
        for (int r = 0; r < 4; r++) {
            float e0 = __expf(acc0[r] * (1.0f / 128.0f) - ws[ct]);
            float e1 = __expf(acc1[r] * (1.0f / 128.0f) - ws[ct]);
            e[ct][0][r] = e0; e[ct][1][r] = e1;
            rs0[r] += e0;     rs1[r] += e1;
        }
        #pragma unroll
        for (int kk = 0; kk < 8; kk++) wcur[kk] = wnxt[kk];
    }

    // ---- phase 3: rowsum reduce across llo lanes, then across waves ----
    #pragma unroll
    for (int m = 1; m <= 8; m <<= 1) {
        #pragma unroll
        for (int r = 0; r < 4; r++) {
            rs0[r] += __shfl_xor(rs0[r], m, 64);
            rs1[r] += __shfl_xor(rs1[r], m, 64);
        }
    }
    if (llo == 0) {
        #pragma unroll
        for (int r = 0; r < 4; r++) {
            red[wave][lhi * 4 + r]      = rs0[r];
            red[wave][16 + lhi * 4 + r] = rs1[r];
        }
    }
    __syncthreads();   // also guarantees all xs reads are done (qs aliases xs)

    float inv0[4], inv1[4];
    #pragma unroll
    for (int r = 0; r < 4; r++) {
        float s0 = 0.f, s1 = 0.f;
        #pragma unroll
        for (int wv = 0; wv < 8; wv++) {
            s0 += red[wv][lhi * 4 + r];
            s1 += red[wv][16 + lhi * 4 + r];
        }
        inv0[r] = 1.0f / s0;
        inv1[r] = 1.0f / s1;
    }

    // ---- phase 4: normalize; write qdist (f32, nt) + q bf16 to LDS ----
    float* qbase = qdist + rowbase * KC;
    #pragma unroll
    for (int ct = 0; ct < 8; ct++) {
        const int col = ct * 16 + llo;
        #pragma unroll
        for (int r = 0; r < 4; r++) {
            const int r0 = lhi * 4 + r, r1 = 16 + lhi * 4 + r;
            float q0 = e[ct][0][r] * inv0[r];
            float q1 = e[ct][1][r] * inv1[r];
            u.qs[wave][r0][col] = f2bf(q0);
            u.qs[wave][r1][col] = f2bf(q1);
            __builtin_nontemporal_store(q0, qbase + r0 * KC + cb + col);
            __builtin_nontemporal_store(q1, qbase + r1 * KC + cb + col);
        }
    }
    __syncthreads();

    // ---- phase 5: PV — wave owns d-cols [wave*32, wave*32+32) ----
    const int wcol = wave * 32;
    f32x4 acc[2][2];
    #pragma unroll
    for (int i = 0; i < 2; i++)
        #pragma unroll
        for (int j = 0; j < 2; j++)
            acc[i][j] = (f32x4){0.f, 0.f, 0.f, 0.f};

    const short* wb0 = wtbf + (size_t)(wcol + llo) * KC + lhi * 8;
    const short* wb1 = wtbf + (size_t)(wcol + 16 + llo) * KC + lhi * 8;

    bf16x8 bcur[2], bnxt[2];
    bcur[0] = *(const bf16x8*)(wb0);
    bcur[1] = *(const bf16x8*)(wb1);

    #pragma unroll
    for (int kc = 0; kc < 32; kc++) {
        if (kc < 31) {
            bnxt[0] = *(const bf16x8*)(wb0 + (kc + 1) * 32);
            bnxt[1] = *(const bf16x8*)(wb1 + (kc + 1) * 32);
        }
        const int sw = kc >> 2;              // source wave buffer
        const int lc = (kc & 3) * 32;        // local code offset in buffer
        const short* qp = &u.qs[sw][llo][lc + lhi * 8];
        bf16x8 a0 = *(const bf16x8*)qp;
        bf16x8 a1 = *(const bf16x8*)(qp + 16 * QLD);
        acc[0][0] = __builtin_amdgcn_mfma_f32_16x16x32_bf16(a0, bcur[0], acc[0][0], 0, 0, 0);
        acc[1][0] = __builtin_amdgcn_mfma_f32_16x16x32_bf16(a1, bcur[0], acc[1][0], 0, 0, 0);
        acc[0][1] = __builtin_amdgcn_mfma_f32_16x16x32_bf16(a0, bcur[1], acc[0][1], 0, 0, 0);
        acc[1][1] = __builtin_amdgcn_mfma_f32_16x16x32_bf16(a1, bcur[1], acc[1][1], 0, 0, 0);
        bcur[0] = bnxt[0];
        bcur[1] = bnxt[1];
    }

    // ---- phase 6: write quantized (nt) ----
    float* obase = quant + rowbase * DD;
    #pragma unroll
    for (int rb = 0; rb < 2; rb++)
        #pragma unroll
        for (int cbi = 0; cbi < 2; cbi++)
            #pragma unroll
            for (int r = 0; r < 4; r++)
                __builtin_nontemporal_store(
                    acc[rb][cbi][r],
                    obase + (rb * 16 + lhi * 4 + r) * DD + wcol + cbi * 16 + llo);
}

// ---------------------------------------------------------------------------
extern "C" void kernel_launch(void* const* d_in, const int* in_sizes, int n_in,
                              void* d_out, int out_size, void* d_ws, size_t ws_size,
                              hipStream_t stream) {
    const float* x = (const float*)d_in[0];
    const float* w = (const float*)d_in[1];
    float* out = (float*)d_out;

    const int nrows = in_sizes[0] / DD;          // 65536
    float* quant = out;                          // [nrows][256]
    float* qdist = out + (size_t)nrows * DD;     // [nrows][1024]

    short* wbf  = (short*)d_ws;                  // 1024*256 bf16 = 512 KB
    short* wtbf = wbf + (size_t)KC * DD;         // 256*1024 bf16 = 512 KB
    float* wsq  = (float*)(wtbf + (size_t)DD * KC);  // 1024 fp32

    prep_kernel<<<KC, DD, 0, stream>>>(w, wbf, wtbf, wsq);
    fused_kernel<<<nrows / BM, 512, 0, stream>>>(x, wbf, wtbf, wsq, qdist, quant);
}

// Round 4
// 273.056 us; speedup vs baseline: 1.0853x; 1.0853x over previous
//
#include <hip/hip_runtime.h>
#include <hip/hip_bf16.h>

#define DD 256
#define KC 1024
#define BM 64

typedef __attribute__((ext_vector_type(4))) float f32x4;
typedef __attribute__((ext_vector_type(8))) short bf16x8;

static __device__ __forceinline__ short f2bf(float f) {
    union { float f; unsigned u; } v; v.f = f;
    unsigned u = v.u;
    unsigned r = u + 0x7fffu + ((u >> 16) & 1u);
    return (short)(r >> 16);
}
static __device__ __forceinline__ float bf2f(short s) {
    union { unsigned u; float f; } v;
    v.u = ((unsigned)(unsigned short)s) << 16;
    return v.f;
}

// ---------------------------------------------------------------------------
// prep: W fp32 [1024][256] -> wbf bf16 [1024][256], wtbf bf16 [256][1024],
//       wsq[k] = sum_d W[k][d]^2 / 256
// ---------------------------------------------------------------------------
__global__ void prep_kernel(const float* __restrict__ w, short* __restrict__ wbf,
                            short* __restrict__ wtbf, float* __restrict__ wsq) {
    const int cod = blockIdx.x;
    const int d   = threadIdx.x;           // 256 threads
    float v = w[cod * DD + d];
    short b = f2bf(v);
    wbf[cod * DD + d] = b;
    wtbf[d * KC + cod] = b;
    float s = v * v;
    #pragma unroll
    for (int m = 32; m >= 1; m >>= 1) s += __shfl_xor(s, m, 64);
    __shared__ float ps[4];
    const int wave = threadIdx.x >> 6, lane = threadIdx.x & 63;
    if (lane == 0) ps[wave] = s;
    __syncthreads();
    if (threadIdx.x == 0) {
        wsq[cod] = (ps[0] + ps[1] + ps[2] + ps[3]) * (1.0f / (float)DD);
    }
}

// ---------------------------------------------------------------------------
// Fused kernel, BM=64 rows/block, 1024 threads (16 waves).
// es[64][1024] bf16 holds exp(logit) (XOR-swizzled granules, no pad).
// Normalization is folded: qdist = e*inv written in a vectorized pass;
// quantized = inv[row] * (e @ W) with inv applied in the PV epilogue.
// Per-block W traffic = 1 MB (vs 2 MB/row-32 before): halved L3 pressure.
// ---------------------------------------------------------------------------
__global__ __launch_bounds__(1024, 4) void fused_kernel(
    const float* __restrict__ x, const short* __restrict__ wbf,
    const short* __restrict__ wtbf, const float* __restrict__ wsq,
    float* __restrict__ qdist, float* __restrict__ quant) {
    __shared__ short es[BM * KC];        // 131072 B; granule-swizzled
    __shared__ short xs[32 * DD];        // 16384 B; granule-swizzled
    __shared__ float red[16][BM];        // 4096 B
    __shared__ float invs[BM];           // 256 B

    const int t    = threadIdx.x;
    const int wave = t >> 6;
    const int lane = t & 63;
    const int lhi  = lane >> 4, llo = lane & 15;
    const long rowbase = (long)blockIdx.x * BM;

    const int cb = wave * 64;            // phase-2: this wave's 64 codes
    float ws4[4];
    #pragma unroll
    for (int ct = 0; ct < 4; ct++) ws4[ct] = wsq[cb + ct * 16 + llo];

    // ================= phase 1+2: scores for two 32-row halves ============
    for (int half = 0; half < 2; ++half) {
        if (half) __syncthreads();       // protect xs from previous readers

        // ---- stage x half-tile (32x256 f32 -> bf16, swizzled) ----
        {
            const int row = t >> 5, g = t & 31;
            const float* xp = x + (rowbase + half * 32 + row) * DD + g * 8;
            f32x4 v0 = __builtin_nontemporal_load((const f32x4*)xp);
            f32x4 v1 = __builtin_nontemporal_load((const f32x4*)xp + 1);
            bf16x8 b;
            b[0] = f2bf(v0[0]); b[1] = f2bf(v0[1]); b[2] = f2bf(v0[2]); b[3] = f2bf(v0[3]);
            b[4] = f2bf(v1[0]); b[5] = f2bf(v1[1]); b[6] = f2bf(v1[2]); b[7] = f2bf(v1[3]);
            *(bf16x8*)((char*)xs + row * 512 + ((g ^ (row & 7)) << 4)) = b;
        }
        __syncthreads();

        // ---- phase 2: wave computes rows[half*32..+32) x codes[cb..cb+64) ----
        bf16x8 wbuf[2][8];
        {
            const short* wr = wbf + (size_t)(cb + llo) * DD + lhi * 8;
            #pragma unroll
            for (int kk = 0; kk < 8; kk++) wbuf[0][kk] = *(const bf16x8*)(wr + kk * 32);
        }
        float rs0[4] = {0.f, 0.f, 0.f, 0.f};
        float rs1[4] = {0.f, 0.f, 0.f, 0.f};

        #pragma unroll
        for (int ct = 0; ct < 4; ct++) {
            if (ct < 3) {
                const short* wr = wbf + (size_t)(cb + (ct + 1) * 16 + llo) * DD + lhi * 8;
                #pragma unroll
                for (int kk = 0; kk < 8; kk++)
                    wbuf[(ct + 1) & 1][kk] = *(const bf16x8*)(wr + kk * 32);
            }
            f32x4 acc0 = {0.f, 0.f, 0.f, 0.f};
            f32x4 acc1 = {0.f, 0.f, 0.f, 0.f};
            #pragma unroll
            for (int kk = 0; kk < 8; kk++) {
                const int off = ((kk * 4 + lhi) ^ (llo & 7)) << 4;
                bf16x8 a0 = *(const bf16x8*)((char*)xs + llo * 512 + off);
                bf16x8 a1 = *(const bf16x8*)((char*)xs + (16 + llo) * 512 + off);
                acc0 = __builtin_amdgcn_mfma_f32_16x16x32_bf16(a0, wbuf[ct & 1][kk], acc0, 0, 0, 0);
                acc1 = __builtin_amdgcn_mfma_f32_16x16x32_bf16(a1, wbuf[ct & 1][kk], acc1, 0, 0, 0);
            }
            const int colg = (cb >> 3) + ct * 2 + (llo >> 3);
            const int cin  = (llo & 7) * 2;
            #pragma unroll
            for (int r = 0; r < 4; r++) {
                float e0 = __expf(acc0[r] * (1.0f / 128.0f) - ws4[ct]);
                float e1 = __expf(acc1[r] * (1.0f / 128.0f) - ws4[ct]);
                rs0[r] += e0; rs1[r] += e1;
                const int row0 = half * 32 + lhi * 4 + r;
                const int row1 = row0 + 16;
                *(short*)((char*)es + row0 * 2048 + ((colg ^ (row0 & 7)) << 4) + cin) = f2bf(e0);
                *(short*)((char*)es + row1 * 2048 + ((colg ^ (row1 & 7)) << 4) + cin) = f2bf(e1);
            }
        }
        // per-row partial sums over this wave's 64 codes
        #pragma unroll
        for (int m = 1; m <= 8; m <<= 1) {
            #pragma unroll
            for (int r = 0; r < 4; r++) {
                rs0[r] += __shfl_xor(rs0[r], m, 64);
                rs1[r] += __shfl_xor(rs1[r], m, 64);
            }
        }
        if (llo == 0) {
            #pragma unroll
            for (int r = 0; r < 4; r++) {
                red[wave][half * 32 + lhi * 4 + r]      = rs0[r];
                red[wave][half * 32 + 16 + lhi * 4 + r] = rs1[r];
            }
        }
    }
    __syncthreads();

    // ================= phase 3: row sums -> invs ==========================
    if (t < BM) {
        float s = 0.f;
        #pragma unroll
        for (int wv = 0; wv < 16; wv++) s += red[wv][t];
        invs[t] = 1.0f / s;
    }
    __syncthreads();

    // ================= phase 4: qdist = e * inv (full-line NT stores) =====
    {
        const int row = t >> 4, cl = t & 15;
        const float invv = invs[row];
        float* qrow = qdist + (rowbase + row) * KC;
        #pragma unroll
        for (int i = 0; i < 8; i++) {
            const int g = cl + i * 16;
            bf16x8 ev = *(const bf16x8*)((char*)es + row * 2048 + ((g ^ (row & 7)) << 4));
            f32x4 o0, o1;
            o0[0] = bf2f(ev[0]) * invv; o0[1] = bf2f(ev[1]) * invv;
            o0[2] = bf2f(ev[2]) * invv; o0[3] = bf2f(ev[3]) * invv;
            o1[0] = bf2f(ev[4]) * invv; o1[1] = bf2f(ev[5]) * invv;
            o1[2] = bf2f(ev[6]) * invv; o1[3] = bf2f(ev[7]) * invv;
            __builtin_nontemporal_store(o0, (f32x4*)(qrow + g * 8));
            __builtin_nontemporal_store(o1, (f32x4*)(qrow + g * 8) + 1);
        }
    }

    // ================= phase 5: quantized = inv * (e @ W) =================
    {
        const int dq = wave * 16;        // this wave's 16 d-columns
        const short* wtp = wtbf + (size_t)(dq + llo) * KC + lhi * 8;
        bf16x8 bb[8];                    // 4-deep ping-pong prefetch
        #pragma unroll
        for (int j = 0; j < 4; j++) bb[j] = *(const bf16x8*)(wtp + j * 32);
        f32x4 acc[4];
        #pragma unroll
        for (int rg = 0; rg < 4; rg++) acc[rg] = (f32x4){0.f, 0.f, 0.f, 0.f};

        #pragma unroll
        for (int g = 0; g < 8; g++) {
            if (g < 7) {
                #pragma unroll
                for (int j = 0; j < 4; j++)
                    bb[(((g + 1) & 1) << 2) + j] = *(const bf16x8*)(wtp + ((g + 1) * 4 + j) * 32);
            }
            #pragma unroll
            for (int j = 0; j < 4; j++) {
                const int kc = g * 4 + j;
                #pragma unroll
                for (int rg = 0; rg < 4; rg++) {
                    const int row = rg * 16 + llo;
                    bf16x8 a = *(const bf16x8*)((char*)es + row * 2048 +
                                                (((kc * 4 + lhi) ^ (llo & 7)) << 4));
                    acc[rg] = __builtin_amdgcn_mfma_f32_16x16x32_bf16(a, bb[((g & 1) << 2) + j], acc[rg], 0, 0, 0);
                }
            }
        }

        float* obase = quant + rowbase * DD + dq;
        #pragma unroll
        for (int rg = 0; rg < 4; rg++)
            #pragma unroll
            for (int r = 0; r < 4; r++) {
                const int row = rg * 16 + lhi * 4 + r;
                obase[row * DD + llo] = acc[rg][r] * invs[row];
            }
    }
}

// ---------------------------------------------------------------------------
extern "C" void kernel_launch(void* const* d_in, const int* in_sizes, int n_in,
                              void* d_out, int out_size, void* d_ws, size_t ws_size,
                              hipStream_t stream) {
    const float* x = (const float*)d_in[0];
    const float* w = (const float*)d_in[1];
    float* out = (float*)d_out;

    const int nrows = in_sizes[0] / DD;          // 65536
    float* quant = out;                          // [nrows][256]
    float* qdist = out + (size_t)nrows * DD;     // [nrows][1024]

    short* wbf  = (short*)d_ws;                  // 1024*256 bf16 = 512 KB
    short* wtbf = wbf + (size_t)KC * DD;         // 256*1024 bf16 = 512 KB
    float* wsq  = (float*)(wtbf + (size_t)DD * KC);  // 1024 fp32

    prep_kernel<<<KC, DD, 0, stream>>>(w, wbf, wtbf, wsq);
    fused_kernel<<<nrows / BM, 1024, 0, stream>>>(x, wbf, wtbf, wsq, qdist, quant);
}